// Round 12
// baseline (167.743 us; speedup 1.0000x reference)
//
#include <hip/hip_runtime.h>
#include <math.h>

#define N_SEQ 1024
#define T_SEQ 64
#define DIMX  32
#define LDIM  256
#define NAUX  128
#define AUXH  128
#define ENCH  256
#define OUTC  288           // DIMX + LDIM
#define DT    0.01f

typedef short bf16x8 __attribute__((ext_vector_type(8)));
typedef float f32x4  __attribute__((ext_vector_type(4)));
typedef unsigned short ush;

__device__ __forceinline__ ush f2bf(float f) {
    unsigned u = __builtin_bit_cast(unsigned, f);
    unsigned r = u + 0x7fffu + ((u >> 16) & 1u);   // RNE
    return (ush)(r >> 16);
}
__device__ __forceinline__ float bf2f(ush h) {
    unsigned u = ((unsigned)h) << 16;
    return __builtin_bit_cast(float, u);
}
__device__ __forceinline__ f32x4 mfma16(bf16x8 a, bf16x8 b, f32x4 c) {
    return __builtin_amdgcn_mfma_f32_16x16x32_bf16(a, b, c, 0, 0, 0);
}

// ---------------------------------------------------------------------------
// K0 "prep": 3 independent jobs, branch on blockIdx —
//   [0,576)      encoder weights -> bf16 T; C_W -> hi/lo bf16 T [32d][256l]
//   [576,3136)   aux W1/W2 -> hi/lo bf16 T (32x32 LDS tile transpose)
//   [3136,3392)  enc0: fp32 encoder for the 1024 t=0 rows (4 rows/block)
// ---------------------------------------------------------------------------
#define CV_ENC   139264
#define PREP_CONV_BLOCKS 576
#define PREP_TR_BLOCKS   2560
#define PREP_ENC0_BLOCKS 256
__global__ __launch_bounds__(256) void prep_kernel(
    const float* __restrict__ eW1, const float* __restrict__ eb1,
    const float* __restrict__ eW2, const float* __restrict__ eb2,
    const float* __restrict__ eW3, const float* __restrict__ C_W,
    const float* __restrict__ aW1, const float* __restrict__ aW2,
    const float* __restrict__ xs,
    ush* __restrict__ encw,
    ush* __restrict__ cwh, ush* __restrict__ cwl,
    ush* __restrict__ a1h, ush* __restrict__ a1l,
    ush* __restrict__ a2h, ush* __restrict__ a2l,
    float* __restrict__ y)
{
    __shared__ float psm[1152];
    const int b   = blockIdx.x;
    const int tid = threadIdx.x;

    if (b < PREP_CONV_BLOCKS) {
        const int idx = b * 256 + tid;
        if (idx < 8192) {
            int c = idx >> 5, k = idx & 31;
            encw[idx] = f2bf(eW1[k * ENCH + c]);
        } else if (idx < 8192 + 65536) {
            int t = idx - 8192; int c = t >> 8, k = t & 255;
            encw[idx] = f2bf(eW2[k * ENCH + c]);
        } else if (idx < CV_ENC) {
            int t = idx - (8192 + 65536); int c = t >> 8, k = t & 255;
            encw[idx] = f2bf(eW3[k * LDIM + c]);
        } else if (idx < CV_ENC + 8192) {
            int t = idx - CV_ENC; int d = t >> 8, l = t & 255;
            float w = C_W[l * DIMX + d];
            ush hi = f2bf(w);
            cwh[t] = hi;
            cwl[t] = f2bf(w - bf2f(hi));
        }
        return;
    }

    if (b < PREP_CONV_BLOCKS + PREP_TR_BLOCKS) {
        float (*tile)[33] = (float(*)[33])psm;
        const int bb0 = b - PREP_CONV_BLOCKS;
        const float* src; ush *dh, *dl; int R, j0, r0;
        if (bb0 < 512) {
            int k = bb0 >> 2; j0 = (bb0 & 3) * 32; r0 = 0; R = 32;
            src = aW1 + (size_t)k * 4096;
            dh = a1h + (size_t)k * 4096; dl = a1l + (size_t)k * 4096;
        } else {
            int bb = bb0 - 512;
            int k = bb >> 4; j0 = ((bb >> 2) & 3) * 32; r0 = (bb & 3) * 32; R = 128;
            src = aW2 + (size_t)k * 16384;
            dh = a2h + (size_t)k * 16384; dl = a2l + (size_t)k * 16384;
        }
        for (int i = tid; i < 1024; i += 256) {
            int rr = i >> 5, jj = i & 31;
            tile[rr][jj] = src[(r0 + rr) * 128 + j0 + jj];
        }
        __syncthreads();
        for (int i = tid; i < 1024; i += 256) {
            int jj = i >> 5, rr = i & 31;
            float w = tile[rr][jj];
            ush hi = f2bf(w);
            int off = (j0 + jj) * R + r0 + rr;
            dh[off] = hi;
            dl[off] = f2bf(w - bf2f(hi));
        }
        return;
    }

    // ---- enc0 ----
    {
        float* Xs  = psm;
        float* Hsf = psm + 128;
        const int c  = tid;
        const int n0 = (b - PREP_CONV_BLOCKS - PREP_TR_BLOCKS) * 4;

        if (tid < 32) {
            int r = tid >> 3, q = tid & 7;
            *(float4*)&Xs[r * 32 + q * 4] =
                *(const float4*)&xs[(size_t)(n0 + r) * (T_SEQ * DIMX) + q * 4];
        }
        __syncthreads();

        float acc[4];
        {
            float w[32];
            #pragma unroll
            for (int d = 0; d < 32; ++d) w[d] = eW1[d * ENCH + c];
            const float bb = eb1[c];
            #pragma unroll
            for (int r = 0; r < 4; ++r) {
                float a = bb;
                #pragma unroll
                for (int d4 = 0; d4 < 8; ++d4) {
                    float4 xv = *(const float4*)&Xs[r * 32 + d4 * 4];
                    a += xv.x * w[d4*4] + xv.y * w[d4*4+1] + xv.z * w[d4*4+2] + xv.w * w[d4*4+3];
                }
                acc[r] = a;
            }
            #pragma unroll
            for (int r = 0; r < 4; ++r) Hsf[r * 256 + c] = fmaxf(acc[r], 0.f);
        }
        __syncthreads();
        {
            const float bb = eb2[c];
            #pragma unroll
            for (int r = 0; r < 4; ++r) acc[r] = bb;
            for (int hc = 0; hc < 8; ++hc) {
                float w[32];
                #pragma unroll
                for (int i = 0; i < 32; ++i) w[i] = eW2[(hc * 32 + i) * ENCH + c];
                #pragma unroll
                for (int r = 0; r < 4; ++r) {
                    float a = acc[r];
                    #pragma unroll
                    for (int h4 = 0; h4 < 8; ++h4) {
                        float4 hv = *(const float4*)&Hsf[r * 256 + hc * 32 + h4 * 4];
                        a += hv.x * w[h4*4] + hv.y * w[h4*4+1] + hv.z * w[h4*4+2] + hv.w * w[h4*4+3];
                    }
                    acc[r] = a;
                }
            }
            __syncthreads();
            #pragma unroll
            for (int r = 0; r < 4; ++r) Hsf[r * 256 + c] = fmaxf(acc[r], 0.f);
        }
        __syncthreads();
        {
            #pragma unroll
            for (int r = 0; r < 4; ++r) acc[r] = 0.f;
            for (int hc = 0; hc < 8; ++hc) {
                float w[32];
                #pragma unroll
                for (int i = 0; i < 32; ++i) w[i] = eW3[(hc * 32 + i) * LDIM + c];
                #pragma unroll
                for (int r = 0; r < 4; ++r) {
                    float a = acc[r];
                    #pragma unroll
                    for (int h4 = 0; h4 < 8; ++h4) {
                        float4 hv = *(const float4*)&Hsf[r * 256 + hc * 32 + h4 * 4];
                        a += hv.x * w[h4*4] + hv.y * w[h4*4+1] + hv.z * w[h4*4+2] + hv.w * w[h4*4+3];
                    }
                    acc[r] = a;
                }
            }
        }
        #pragma unroll
        for (int r = 0; r < 4; ++r)
            y[((size_t)(n0 + r) * T_SEQ) * OUTC + DIMX + c] = acc[r];
    }
}

// ---------------------------------------------------------------------------
// K1: aux MLPs — register-resident weights (R11-validated).
// ---------------------------------------------------------------------------
__global__ __launch_bounds__(256) void auxm_kernel(
    const float* __restrict__ xs,
    const ush* __restrict__ W1h, const ush* __restrict__ W1l,
    const float* __restrict__ b1,
    const ush* __restrict__ W2h, const ush* __restrict__ W2l,
    const float* __restrict__ b2,
    const float* __restrict__ W3,
    float* __restrict__ a_ws, float* __restrict__ th_ws)
{
    const int k   = blockIdx.x >> 2;
    const int qn  = blockIdx.x & 3;
    const int tid = threadIdx.x;
    const int wv  = tid >> 6;
    const int ln  = tid & 63;
    const int lr  = ln & 15;
    const int g   = ln >> 4;
    const int cb  = wv * 32;

    __shared__ ush   x0h[64][40];
    __shared__ ush   x0l[64][40];
    __shared__ ush   h1h[64][136];
    __shared__ ush   h1l[64][136];
    __shared__ float w3s[256];
    __shared__ float p3[256];

    bf16x8 w1bh[2], w1bl[2], w2bh[4][2], w2bl[4][2];
    {
        const ush* W1hk = W1h + (size_t)k * 4096;
        const ush* W1lk = W1l + (size_t)k * 4096;
        #pragma unroll
        for (int ct = 0; ct < 2; ++ct) {
            int off = (cb + ct * 16 + lr) * 32 + g * 8;
            w1bh[ct] = *(const bf16x8*)&W1hk[off];
            w1bl[ct] = *(const bf16x8*)&W1lk[off];
        }
        const ush* W2hk = W2h + (size_t)k * 16384;
        const ush* W2lk = W2l + (size_t)k * 16384;
        #pragma unroll
        for (int kk = 0; kk < 4; ++kk)
            #pragma unroll
            for (int ct = 0; ct < 2; ++ct) {
                int off = (cb + ct * 16 + lr) * 128 + kk * 32 + g * 8;
                w2bh[kk][ct] = *(const bf16x8*)&W2hk[off];
                w2bl[kk][ct] = *(const bf16x8*)&W2lk[off];
            }
    }
    w3s[tid] = W3[(size_t)k * (AUXH * 2) + tid];

    const float bb1[2] = { b1[k * 128 + cb + lr], b1[k * 128 + cb + 16 + lr] };
    const float bb2[2] = { b2[k * 128 + cb + lr], b2[k * 128 + cb + 16 + lr] };

    for (int t8 = 0; t8 < 4; ++t8) {
        const int n0 = qn * 256 + t8 * 64;
        __syncthreads();

        for (int i = tid; i < 512; i += 256) {
            int r = i >> 3, qd = i & 7;
            float4 v = *(const float4*)&xs[(size_t)(n0 + r) * (T_SEQ * DIMX) + qd * 4];
            short4 hs, ls;
            float vv[4] = {v.x, v.y, v.z, v.w};
            short* hp = (short*)&hs; short* lp = (short*)&ls;
            #pragma unroll
            for (int u = 0; u < 4; ++u) {
                ush hi = f2bf(vv[u]);
                hp[u] = (short)hi;
                lp[u] = (short)f2bf(vv[u] - bf2f(hi));
            }
            *(short4*)&x0h[r][qd * 4] = hs;
            *(short4*)&x0l[r][qd * 4] = ls;
        }
        __syncthreads();

        // layer 1
        {
            f32x4 acc[4][2];
            #pragma unroll
            for (int rt = 0; rt < 4; ++rt) {
                bf16x8 ah = *(const bf16x8*)&x0h[rt * 16 + lr][g * 8];
                bf16x8 al = *(const bf16x8*)&x0l[rt * 16 + lr][g * 8];
                #pragma unroll
                for (int ct = 0; ct < 2; ++ct) {
                    f32x4 z = {0.f, 0.f, 0.f, 0.f};
                    z = mfma16(ah, w1bl[ct], z);
                    z = mfma16(al, w1bh[ct], z);
                    acc[rt][ct] = mfma16(ah, w1bh[ct], z);
                }
            }
            #pragma unroll
            for (int ct = 0; ct < 2; ++ct) {
                const int col = cb + ct * 16 + lr;
                #pragma unroll
                for (int rt = 0; rt < 4; ++rt)
                    #pragma unroll
                    for (int i = 0; i < 4; ++i) {
                        float h = fmaxf(acc[rt][ct][i] + bb1[ct], 0.f);
                        ush hi = f2bf(h);
                        int row = rt * 16 + g * 4 + i;
                        h1h[row][col] = hi;
                        h1l[row][col] = f2bf(h - bf2f(hi));
                    }
            }
        }
        __syncthreads();

        // layer 2
        {
            f32x4 acc[4][2];
            #pragma unroll
            for (int rt = 0; rt < 4; ++rt)
                #pragma unroll
                for (int ct = 0; ct < 2; ++ct) acc[rt][ct] = (f32x4){0.f,0.f,0.f,0.f};

            #pragma unroll
            for (int kk = 0; kk < 4; ++kk) {
                bf16x8 ah[4], al[4];
                #pragma unroll
                for (int rt = 0; rt < 4; ++rt) {
                    ah[rt] = *(const bf16x8*)&h1h[rt * 16 + lr][kk * 32 + g * 8];
                    al[rt] = *(const bf16x8*)&h1l[rt * 16 + lr][kk * 32 + g * 8];
                }
                #pragma unroll
                for (int rt = 0; rt < 4; ++rt)
                    #pragma unroll
                    for (int ct = 0; ct < 2; ++ct) {
                        f32x4 z = acc[rt][ct];
                        z = mfma16(ah[rt], w2bl[kk][ct], z);
                        z = mfma16(al[rt], w2bh[kk][ct], z);
                        acc[rt][ct] = mfma16(ah[rt], w2bh[kk][ct], z);
                    }
            }
            __syncthreads();
            #pragma unroll
            for (int ct = 0; ct < 2; ++ct) {
                const int col = cb + ct * 16 + lr;
                #pragma unroll
                for (int rt = 0; rt < 4; ++rt)
                    #pragma unroll
                    for (int i = 0; i < 4; ++i) {
                        float h = fmaxf(acc[rt][ct][i] + bb2[ct], 0.f);
                        ush hi = f2bf(h);
                        int row = rt * 16 + g * 4 + i;
                        h1h[row][col] = hi;
                        h1l[row][col] = f2bf(h - bf2f(hi));
                    }
            }
        }
        __syncthreads();

        // layer 3
        {
            const int hh = tid >> 7, r = tid & 127, n = r >> 1, o = r & 1;
            float s = 0.f;
            #pragma unroll
            for (int h8 = hh * 64; h8 < hh * 64 + 64; h8 += 8) {
                bf16x8 vh = *(const bf16x8*)&h1h[n][h8];
                bf16x8 vl = *(const bf16x8*)&h1l[n][h8];
                #pragma unroll
                for (int u = 0; u < 8; ++u) {
                    float hv = bf2f((ush)vh[u]) + bf2f((ush)vl[u]);
                    s += hv * w3s[(h8 + u) * 2 + o];
                }
            }
            p3[tid] = s;
        }
        __syncthreads();
        if (tid < 128) {
            const int n = tid >> 1, o = tid & 1;
            float v = (p3[tid] + p3[tid + 128]) * DT;
            float* dst = o ? th_ws : a_ws;
            dst[(size_t)(n0 + n) * NAUX + k] = v;
        }
    }
}

// ---------------------------------------------------------------------------
// K2: encoder via bf16 MFMA (R8-proven; skip-t0-e-cols epilogue).
// ---------------------------------------------------------------------------
__global__ __launch_bounds__(256) void encm_kernel(
    const float* __restrict__ xs,
    const ush* __restrict__ W1T, const float* __restrict__ b1,
    const ush* __restrict__ W2T, const float* __restrict__ b2,
    const ush* __restrict__ W3T,
    float* __restrict__ y)
{
    __shared__ float Xf[64 * 36];
    __shared__ ush   Hs[64 * 264];

    const int tid = threadIdx.x;
    const int wv  = tid >> 6;
    const int ln  = tid & 63;
    const int lr  = ln & 15;
    const int g   = ln >> 4;
    const int cb  = wv * 64;
    const size_t row0 = (size_t)blockIdx.x * 64;

    {
        const float4* src = (const float4*)(xs + row0 * DIMX);
        for (int i = tid; i < 512; i += 256) {
            int r = i >> 3, q = i & 7;
            *(float4*)&Xf[r * 36 + q * 4] = src[i];
        }
    }
    __syncthreads();

    // layer 1 (K=32)
    {
        f32x4 acc[4][4];
        bf16x8 bfr[4], afr[4];
        #pragma unroll
        for (int ct = 0; ct < 4; ++ct)
            bfr[ct] = *(const bf16x8*)&W1T[(cb + ct * 16 + lr) * 32 + g * 8];
        #pragma unroll
        for (int rt = 0; rt < 4; ++rt) {
            const float* xp = &Xf[(rt * 16 + lr) * 36 + g * 8];
            float4 u = *(const float4*)xp;
            float4 v = *(const float4*)(xp + 4);
            bf16x8 t;
            t[0]=(short)f2bf(u.x); t[1]=(short)f2bf(u.y); t[2]=(short)f2bf(u.z); t[3]=(short)f2bf(u.w);
            t[4]=(short)f2bf(v.x); t[5]=(short)f2bf(v.y); t[6]=(short)f2bf(v.z); t[7]=(short)f2bf(v.w);
            afr[rt] = t;
        }
        #pragma unroll
        for (int rt = 0; rt < 4; ++rt)
            #pragma unroll
            for (int ct = 0; ct < 4; ++ct) {
                f32x4 z = {0.f, 0.f, 0.f, 0.f};
                acc[rt][ct] = mfma16(afr[rt], bfr[ct], z);
            }
        #pragma unroll
        for (int ct = 0; ct < 4; ++ct) {
            const float bb = b1[cb + ct * 16 + lr];
            #pragma unroll
            for (int rt = 0; rt < 4; ++rt)
                #pragma unroll
                for (int i = 0; i < 4; ++i) {
                    float h = fmaxf(acc[rt][ct][i] + bb, 0.f);
                    Hs[(rt * 16 + g * 4 + i) * 264 + cb + ct * 16 + lr] = f2bf(h);
                }
        }
    }
    __syncthreads();

    int wrow[4], hoff[4];
    #pragma unroll
    for (int ct = 0; ct < 4; ++ct) wrow[ct] = (cb + ct * 16 + lr) * 256 + g * 8;
    #pragma unroll
    for (int rt = 0; rt < 4; ++rt) hoff[rt] = (rt * 16 + lr) * 264 + g * 8;

    // layer 2 (K=256)
    {
        f32x4 acc[4][4];
        #pragma unroll
        for (int rt = 0; rt < 4; ++rt)
            #pragma unroll
            for (int ct = 0; ct < 4; ++ct) acc[rt][ct] = (f32x4){0.f,0.f,0.f,0.f};
        #pragma unroll 2
        for (int kk = 0; kk < 8; ++kk) {
            bf16x8 bfr[4], afr[4];
            #pragma unroll
            for (int ct = 0; ct < 4; ++ct)
                bfr[ct] = *(const bf16x8*)&W2T[wrow[ct] + kk * 32];
            #pragma unroll
            for (int rt = 0; rt < 4; ++rt)
                afr[rt] = *(const bf16x8*)&Hs[hoff[rt] + kk * 32];
            #pragma unroll
            for (int rt = 0; rt < 4; ++rt)
                #pragma unroll
                for (int ct = 0; ct < 4; ++ct)
                    acc[rt][ct] = mfma16(afr[rt], bfr[ct], acc[rt][ct]);
        }
        __syncthreads();
        #pragma unroll
        for (int ct = 0; ct < 4; ++ct) {
            const float bb = b2[cb + ct * 16 + lr];
            #pragma unroll
            for (int rt = 0; rt < 4; ++rt)
                #pragma unroll
                for (int i = 0; i < 4; ++i) {
                    float h = fmaxf(acc[rt][ct][i] + bb, 0.f);
                    Hs[(rt * 16 + g * 4 + i) * 264 + cb + ct * 16 + lr] = f2bf(h);
                }
        }
    }
    __syncthreads();

    // layer 3 (K=256) + coalesced two-pass store (skip t=0 e-cols)
    {
        f32x4 acc[4][4];
        #pragma unroll
        for (int rt = 0; rt < 4; ++rt)
            #pragma unroll
            for (int ct = 0; ct < 4; ++ct) acc[rt][ct] = (f32x4){0.f,0.f,0.f,0.f};
        #pragma unroll 2
        for (int kk = 0; kk < 8; ++kk) {
            bf16x8 bfr[4], afr[4];
            #pragma unroll
            for (int ct = 0; ct < 4; ++ct)
                bfr[ct] = *(const bf16x8*)&W3T[wrow[ct] + kk * 32];
            #pragma unroll
            for (int rt = 0; rt < 4; ++rt)
                afr[rt] = *(const bf16x8*)&Hs[hoff[rt] + kk * 32];
            #pragma unroll
            for (int rt = 0; rt < 4; ++rt)
                #pragma unroll
                for (int ct = 0; ct < 4; ++ct)
                    acc[rt][ct] = mfma16(afr[rt], bfr[ct], acc[rt][ct]);
        }
        __syncthreads();

        float* HsF = (float*)Hs;
        const int r  = tid >> 3;
        const int ce = tid & 7;

        #pragma unroll
        for (int p = 0; p < 2; ++p) {
            #pragma unroll
            for (int rt = 2 * p; rt < 2 * p + 2; ++rt)
                #pragma unroll
                for (int ct = 0; ct < 4; ++ct)
                    #pragma unroll
                    for (int i = 0; i < 4; ++i)
                        HsF[((rt - 2 * p) * 16 + g * 4 + i) * 264 + cb + ct * 16 + lr]
                            = acc[rt][ct][i];
            __syncthreads();
            const int rloc = p * 32 + r;
            float* dstrow = &y[(row0 + rloc) * OUTC];
            #pragma unroll
            for (int j = 0; j < 9; ++j) {
                int f4 = j * 8 + ce;
                float4 v;
                if (f4 < 8) v = *(const float4*)&Xf[rloc * 36 + f4 * 4];
                else        v = *(const float4*)&HsF[r * 264 + (f4 - 8) * 4];
                if (!(rloc == 0 && f4 >= 8))
                    *(float4*)&dstrow[f4 * 4] = v;
            }
            __syncthreads();
        }
    }
}

// ---------------------------------------------------------------------------
// K3: scan_lite — closed-form z^t, streams y_lat into yp. No LDS, no readout.
// ---------------------------------------------------------------------------
__global__ __launch_bounds__(256) void scan_lite_kernel(
    const float* __restrict__ a_ws, const float* __restrict__ th_ws,
    const float* __restrict__ y,
    float* __restrict__ yp)
{
    const int n = blockIdx.x >> 2;
    const int q = blockIdx.x & 3;
    const int e = threadIdx.x;
    const int k = e >> 1;

    const float* yrow0 = y + (size_t)n * T_SEQ * OUTC + DIMX;
    float2 y0 = *(const float2*)&yrow0[e & ~1];
    const float a  = a_ws [n * NAUX + k];
    const float th = th_ws[n * NAUX + k];

    const float m = expf(a);
    float ss, cc; sincosf(th, &ss, &cc);
    const float zr = m * cc, zi = m * ss;

    float pr = zr, pi = zi;
    #pragma unroll
    for (int s2 = 0; s2 < 4; ++s2) {
        float nr = pr * pr - pi * pi;
        pi = 2.f * pr * pi; pr = nr;
    }
    float wr = 1.f, wi = 0.f;
    for (int j = 0; j < q; ++j) {
        float nr = wr * pr - wi * pi;
        wi = wr * pi + wi * pr; wr = nr;
    }

    const bool imag = e & 1;
    float* ypn = yp + (size_t)n * T_SEQ * OUTC;

    #pragma unroll 4
    for (int tl = 0; tl < 16; ++tl) {
        const int t = q * 16 + tl;
        float val = imag ? (y0.x * wi + y0.y * wr)
                         : (y0.x * wr - y0.y * wi);
        ypn[(size_t)t * OUTC + DIMX + e] = val;
        float nwr = wr * zr - wi * zi;
        wi = wr * zi + wi * zr;
        wr = nwr;
    }
}

// ---------------------------------------------------------------------------
// K4: xpred — x_pred = ys @ C_W as split-bf16 MFMA GEMM over yp's latent
// rows. Block = one n (64 rows x 256 l). Staging = auxm's validated hi/lo
// pattern; fragments/3-product = auxm-L1's validated pattern; B = cwh/cwl.
// ---------------------------------------------------------------------------
__global__ __launch_bounds__(256) void xpred_kernel(
    const float* __restrict__ xs,
    const ush* __restrict__ cwh, const ush* __restrict__ cwl,
    float* __restrict__ yp)
{
    __shared__ ush ysh[64][264];   // 33.8 KB
    __shared__ ush ysl[64][264];   // 33.8 KB

    const int tid = threadIdx.x;
    const int wv  = tid >> 6;
    const int ln  = tid & 63;
    const int lr  = ln & 15;
    const int g   = ln >> 4;
    const int n   = blockIdx.x;
    const size_t row0 = (size_t)n * 64;

    // stage yp latent rows -> hi/lo bf16 LDS
    for (int i = tid; i < 4096; i += 256) {
        int r = i >> 6, f4 = i & 63;
        float4 v = *(const float4*)&yp[(row0 + r) * OUTC + DIMX + f4 * 4];
        short4 hs, ls;
        float vv[4] = {v.x, v.y, v.z, v.w};
        short* hp = (short*)&hs; short* lp = (short*)&ls;
        #pragma unroll
        for (int u = 0; u < 4; ++u) {
            ush hi = f2bf(vv[u]);
            hp[u] = (short)hi;
            lp[u] = (short)f2bf(vv[u] - bf2f(hi));
        }
        *(short4*)&ysh[r][f4 * 4] = hs;
        *(short4*)&ysl[r][f4 * 4] = ls;
    }
    __syncthreads();

    // MFMA: wave wv owns rows wv*16..+15; ct = 0,1 covers d 0..31
    f32x4 acc[2];
    acc[0] = (f32x4){0.f, 0.f, 0.f, 0.f};
    acc[1] = (f32x4){0.f, 0.f, 0.f, 0.f};
    #pragma unroll
    for (int kk = 0; kk < 8; ++kk) {
        bf16x8 ah = *(const bf16x8*)&ysh[wv * 16 + lr][kk * 32 + g * 8];
        bf16x8 al = *(const bf16x8*)&ysl[wv * 16 + lr][kk * 32 + g * 8];
        #pragma unroll
        for (int ct = 0; ct < 2; ++ct) {
            const int off = (ct * 16 + lr) * 256 + kk * 32 + g * 8;
            bf16x8 bh = *(const bf16x8*)&cwh[off];
            bf16x8 bl = *(const bf16x8*)&cwl[off];
            acc[ct] = mfma16(ah, bl, acc[ct]);
            acc[ct] = mfma16(al, bh, acc[ct]);
            acc[ct] = mfma16(ah, bh, acc[ct]);
        }
    }

    // write x_pred (cols 0..31); t=0 row overridden with xs
    #pragma unroll
    for (int ct = 0; ct < 2; ++ct) {
        const int d = ct * 16 + lr;
        #pragma unroll
        for (int i = 0; i < 4; ++i) {
            const int rloc = wv * 16 + g * 4 + i;
            float o = acc[ct][i];
            if (rloc == 0) o = xs[(size_t)n * (T_SEQ * DIMX) + d];
            yp[(row0 + rloc) * OUTC + d] = o;
        }
    }
}

// ---------------------------------------------------------------------------
extern "C" void kernel_launch(void* const* d_in, const int* in_sizes, int n_in,
                              void* d_out, int out_size, void* d_ws, size_t ws_size,
                              hipStream_t stream)
{
    const float* xs   = (const float*)d_in[0];
    const float* eW1  = (const float*)d_in[1];
    const float* eb1  = (const float*)d_in[2];
    const float* eW2  = (const float*)d_in[3];
    const float* eb2  = (const float*)d_in[4];
    const float* eW3  = (const float*)d_in[5];
    const float* aW1  = (const float*)d_in[6];
    const float* ab1  = (const float*)d_in[7];
    const float* aW2  = (const float*)d_in[8];
    const float* ab2  = (const float*)d_in[9];
    const float* aW3  = (const float*)d_in[10];
    const float* C_W  = (const float*)d_in[11];

    float* y  = (float*)d_out;
    float* yp = y + (size_t)N_SEQ * T_SEQ * OUTC;

    float* a_ws  = (float*)d_ws;
    float* th_ws = a_ws + (size_t)N_SEQ * NAUX;
    ush* encw = (ush*)(th_ws + (size_t)N_SEQ * NAUX);
    ush* W1T = encw;
    ush* W2T = encw + 8192;
    ush* W3T = encw + 8192 + 65536;
    ush* a1h = encw + CV_ENC;
    ush* a1l = a1h + 524288;
    ush* a2h = a1l + 524288;
    ush* a2l = a2h + 2097152;
    ush* cwh = a2l + 2097152;
    ush* cwl = cwh + 8192;

    prep_kernel<<<PREP_CONV_BLOCKS + PREP_TR_BLOCKS + PREP_ENC0_BLOCKS, 256, 0, stream>>>(
        eW1, eb1, eW2, eb2, eW3, C_W, aW1, aW2, xs,
        encw, cwh, cwl, a1h, a1l, a2h, a2l, y);
    auxm_kernel<<<512, 256, 0, stream>>>(
        xs, a1h, a1l, ab1, a2h, a2l, ab2, aW3, a_ws, th_ws);
    encm_kernel<<<N_SEQ * T_SEQ / 64, 256, 0, stream>>>(
        xs, W1T, eb1, W2T, eb2, W3T, y);
    scan_lite_kernel<<<N_SEQ * 4, 256, 0, stream>>>(a_ws, th_ws, y, yp);
    xpred_kernel<<<N_SEQ, 256, 0, stream>>>(xs, cwh, cwl, yp);
}

// Round 13
// 163.500 us; speedup vs baseline: 1.0260x; 1.0260x over previous
//
#include <hip/hip_runtime.h>
#include <math.h>

#define N_SEQ 1024
#define T_SEQ 64
#define DIMX  32
#define LDIM  256
#define NAUX  128
#define AUXH  128
#define ENCH  256
#define OUTC  288           // DIMX + LDIM
#define DT    0.01f

typedef short bf16x8 __attribute__((ext_vector_type(8)));
typedef float f32x4  __attribute__((ext_vector_type(4)));
typedef unsigned short ush;

__device__ __forceinline__ ush f2bf(float f) {
    unsigned u = __builtin_bit_cast(unsigned, f);
    unsigned r = u + 0x7fffu + ((u >> 16) & 1u);   // RNE
    return (ush)(r >> 16);
}
__device__ __forceinline__ float bf2f(ush h) {
    unsigned u = ((unsigned)h) << 16;
    return __builtin_bit_cast(float, u);
}
__device__ __forceinline__ f32x4 mfma16(bf16x8 a, bf16x8 b, f32x4 c) {
    return __builtin_amdgcn_mfma_f32_16x16x32_bf16(a, b, c, 0, 0, 0);
}

// ---------------------------------------------------------------------------
// K0 "prep": 3 independent jobs, branch on blockIdx (R11-validated) —
//   [0,576)      encoder weights -> bf16 T; C_W -> fp32 T
//   [576,3136)   aux W1/W2 -> hi/lo bf16 T (32x32 LDS tile transpose)
//   [3136,3392)  enc0: fp32 encoder for the 1024 t=0 rows (4 rows/block)
// ---------------------------------------------------------------------------
#define CV_ENC   139264
#define PREP_CONV_BLOCKS 576
#define PREP_TR_BLOCKS   2560
#define PREP_ENC0_BLOCKS 256
__global__ __launch_bounds__(256) void prep_kernel(
    const float* __restrict__ eW1, const float* __restrict__ eb1,
    const float* __restrict__ eW2, const float* __restrict__ eb2,
    const float* __restrict__ eW3, const float* __restrict__ C_W,
    const float* __restrict__ aW1, const float* __restrict__ aW2,
    const float* __restrict__ xs,
    ush* __restrict__ encw, float* __restrict__ cwt,
    ush* __restrict__ a1h, ush* __restrict__ a1l,
    ush* __restrict__ a2h, ush* __restrict__ a2l,
    float* __restrict__ y)
{
    __shared__ float psm[1152];
    const int b   = blockIdx.x;
    const int tid = threadIdx.x;

    if (b < PREP_CONV_BLOCKS) {
        const int idx = b * 256 + tid;
        if (idx < 8192) {
            int c = idx >> 5, k = idx & 31;
            encw[idx] = f2bf(eW1[k * ENCH + c]);
        } else if (idx < 8192 + 65536) {
            int t = idx - 8192; int c = t >> 8, k = t & 255;
            encw[idx] = f2bf(eW2[k * ENCH + c]);
        } else if (idx < CV_ENC) {
            int t = idx - (8192 + 65536); int c = t >> 8, k = t & 255;
            encw[idx] = f2bf(eW3[k * LDIM + c]);
        } else if (idx < CV_ENC + 8192) {
            int t = idx - CV_ENC; int d = t >> 8, l = t & 255;
            cwt[t] = C_W[l * DIMX + d];
        }
        return;
    }

    if (b < PREP_CONV_BLOCKS + PREP_TR_BLOCKS) {
        float (*tile)[33] = (float(*)[33])psm;
        const int bb0 = b - PREP_CONV_BLOCKS;
        const float* src; ush *dh, *dl; int R, j0, r0;
        if (bb0 < 512) {
            int k = bb0 >> 2; j0 = (bb0 & 3) * 32; r0 = 0; R = 32;
            src = aW1 + (size_t)k * 4096;
            dh = a1h + (size_t)k * 4096; dl = a1l + (size_t)k * 4096;
        } else {
            int bb = bb0 - 512;
            int k = bb >> 4; j0 = ((bb >> 2) & 3) * 32; r0 = (bb & 3) * 32; R = 128;
            src = aW2 + (size_t)k * 16384;
            dh = a2h + (size_t)k * 16384; dl = a2l + (size_t)k * 16384;
        }
        for (int i = tid; i < 1024; i += 256) {
            int rr = i >> 5, jj = i & 31;
            tile[rr][jj] = src[(r0 + rr) * 128 + j0 + jj];
        }
        __syncthreads();
        for (int i = tid; i < 1024; i += 256) {
            int jj = i >> 5, rr = i & 31;
            float w = tile[rr][jj];
            ush hi = f2bf(w);
            int off = (j0 + jj) * R + r0 + rr;
            dh[off] = hi;
            dl[off] = f2bf(w - bf2f(hi));
        }
        return;
    }

    // ---- enc0 ----
    {
        float* Xs  = psm;
        float* Hsf = psm + 128;
        const int c  = tid;
        const int n0 = (b - PREP_CONV_BLOCKS - PREP_TR_BLOCKS) * 4;

        if (tid < 32) {
            int r = tid >> 3, q = tid & 7;
            *(float4*)&Xs[r * 32 + q * 4] =
                *(const float4*)&xs[(size_t)(n0 + r) * (T_SEQ * DIMX) + q * 4];
        }
        __syncthreads();

        float acc[4];
        {
            float w[32];
            #pragma unroll
            for (int d = 0; d < 32; ++d) w[d] = eW1[d * ENCH + c];
            const float bb = eb1[c];
            #pragma unroll
            for (int r = 0; r < 4; ++r) {
                float a = bb;
                #pragma unroll
                for (int d4 = 0; d4 < 8; ++d4) {
                    float4 xv = *(const float4*)&Xs[r * 32 + d4 * 4];
                    a += xv.x * w[d4*4] + xv.y * w[d4*4+1] + xv.z * w[d4*4+2] + xv.w * w[d4*4+3];
                }
                acc[r] = a;
            }
            #pragma unroll
            for (int r = 0; r < 4; ++r) Hsf[r * 256 + c] = fmaxf(acc[r], 0.f);
        }
        __syncthreads();
        {
            const float bb = eb2[c];
            #pragma unroll
            for (int r = 0; r < 4; ++r) acc[r] = bb;
            for (int hc = 0; hc < 8; ++hc) {
                float w[32];
                #pragma unroll
                for (int i = 0; i < 32; ++i) w[i] = eW2[(hc * 32 + i) * ENCH + c];
                #pragma unroll
                for (int r = 0; r < 4; ++r) {
                    float a = acc[r];
                    #pragma unroll
                    for (int h4 = 0; h4 < 8; ++h4) {
                        float4 hv = *(const float4*)&Hsf[r * 256 + hc * 32 + h4 * 4];
                        a += hv.x * w[h4*4] + hv.y * w[h4*4+1] + hv.z * w[h4*4+2] + hv.w * w[h4*4+3];
                    }
                    acc[r] = a;
                }
            }
            __syncthreads();
            #pragma unroll
            for (int r = 0; r < 4; ++r) Hsf[r * 256 + c] = fmaxf(acc[r], 0.f);
        }
        __syncthreads();
        {
            #pragma unroll
            for (int r = 0; r < 4; ++r) acc[r] = 0.f;
            for (int hc = 0; hc < 8; ++hc) {
                float w[32];
                #pragma unroll
                for (int i = 0; i < 32; ++i) w[i] = eW3[(hc * 32 + i) * LDIM + c];
                #pragma unroll
                for (int r = 0; r < 4; ++r) {
                    float a = acc[r];
                    #pragma unroll
                    for (int h4 = 0; h4 < 8; ++h4) {
                        float4 hv = *(const float4*)&Hsf[r * 256 + hc * 32 + h4 * 4];
                        a += hv.x * w[h4*4] + hv.y * w[h4*4+1] + hv.z * w[h4*4+2] + hv.w * w[h4*4+3];
                    }
                    acc[r] = a;
                }
            }
        }
        #pragma unroll
        for (int r = 0; r < 4; ++r)
            y[((size_t)(n0 + r) * T_SEQ) * OUTC + DIMX + c] = acc[r];
    }
}

// ---------------------------------------------------------------------------
// K1: aux MLPs — register-resident weights (R11-validated, unchanged).
// ---------------------------------------------------------------------------
__global__ __launch_bounds__(256) void auxm_kernel(
    const float* __restrict__ xs,
    const ush* __restrict__ W1h, const ush* __restrict__ W1l,
    const float* __restrict__ b1,
    const ush* __restrict__ W2h, const ush* __restrict__ W2l,
    const float* __restrict__ b2,
    const float* __restrict__ W3,
    float* __restrict__ a_ws, float* __restrict__ th_ws)
{
    const int k   = blockIdx.x >> 2;
    const int qn  = blockIdx.x & 3;
    const int tid = threadIdx.x;
    const int wv  = tid >> 6;
    const int ln  = tid & 63;
    const int lr  = ln & 15;
    const int g   = ln >> 4;
    const int cb  = wv * 32;

    __shared__ ush   x0h[64][40];
    __shared__ ush   x0l[64][40];
    __shared__ ush   h1h[64][136];
    __shared__ ush   h1l[64][136];
    __shared__ float w3s[256];
    __shared__ float p3[256];

    bf16x8 w1bh[2], w1bl[2], w2bh[4][2], w2bl[4][2];
    {
        const ush* W1hk = W1h + (size_t)k * 4096;
        const ush* W1lk = W1l + (size_t)k * 4096;
        #pragma unroll
        for (int ct = 0; ct < 2; ++ct) {
            int off = (cb + ct * 16 + lr) * 32 + g * 8;
            w1bh[ct] = *(const bf16x8*)&W1hk[off];
            w1bl[ct] = *(const bf16x8*)&W1lk[off];
        }
        const ush* W2hk = W2h + (size_t)k * 16384;
        const ush* W2lk = W2l + (size_t)k * 16384;
        #pragma unroll
        for (int kk = 0; kk < 4; ++kk)
            #pragma unroll
            for (int ct = 0; ct < 2; ++ct) {
                int off = (cb + ct * 16 + lr) * 128 + kk * 32 + g * 8;
                w2bh[kk][ct] = *(const bf16x8*)&W2hk[off];
                w2bl[kk][ct] = *(const bf16x8*)&W2lk[off];
            }
    }
    w3s[tid] = W3[(size_t)k * (AUXH * 2) + tid];

    const float bb1[2] = { b1[k * 128 + cb + lr], b1[k * 128 + cb + 16 + lr] };
    const float bb2[2] = { b2[k * 128 + cb + lr], b2[k * 128 + cb + 16 + lr] };

    for (int t8 = 0; t8 < 4; ++t8) {
        const int n0 = qn * 256 + t8 * 64;
        __syncthreads();

        for (int i = tid; i < 512; i += 256) {
            int r = i >> 3, qd = i & 7;
            float4 v = *(const float4*)&xs[(size_t)(n0 + r) * (T_SEQ * DIMX) + qd * 4];
            short4 hs, ls;
            float vv[4] = {v.x, v.y, v.z, v.w};
            short* hp = (short*)&hs; short* lp = (short*)&ls;
            #pragma unroll
            for (int u = 0; u < 4; ++u) {
                ush hi = f2bf(vv[u]);
                hp[u] = (short)hi;
                lp[u] = (short)f2bf(vv[u] - bf2f(hi));
            }
            *(short4*)&x0h[r][qd * 4] = hs;
            *(short4*)&x0l[r][qd * 4] = ls;
        }
        __syncthreads();

        // layer 1
        {
            f32x4 acc[4][2];
            #pragma unroll
            for (int rt = 0; rt < 4; ++rt) {
                bf16x8 ah = *(const bf16x8*)&x0h[rt * 16 + lr][g * 8];
                bf16x8 al = *(const bf16x8*)&x0l[rt * 16 + lr][g * 8];
                #pragma unroll
                for (int ct = 0; ct < 2; ++ct) {
                    f32x4 z = {0.f, 0.f, 0.f, 0.f};
                    z = mfma16(ah, w1bl[ct], z);
                    z = mfma16(al, w1bh[ct], z);
                    acc[rt][ct] = mfma16(ah, w1bh[ct], z);
                }
            }
            #pragma unroll
            for (int ct = 0; ct < 2; ++ct) {
                const int col = cb + ct * 16 + lr;
                #pragma unroll
                for (int rt = 0; rt < 4; ++rt)
                    #pragma unroll
                    for (int i = 0; i < 4; ++i) {
                        float h = fmaxf(acc[rt][ct][i] + bb1[ct], 0.f);
                        ush hi = f2bf(h);
                        int row = rt * 16 + g * 4 + i;
                        h1h[row][col] = hi;
                        h1l[row][col] = f2bf(h - bf2f(hi));
                    }
            }
        }
        __syncthreads();

        // layer 2
        {
            f32x4 acc[4][2];
            #pragma unroll
            for (int rt = 0; rt < 4; ++rt)
                #pragma unroll
                for (int ct = 0; ct < 2; ++ct) acc[rt][ct] = (f32x4){0.f,0.f,0.f,0.f};

            #pragma unroll
            for (int kk = 0; kk < 4; ++kk) {
                bf16x8 ah[4], al[4];
                #pragma unroll
                for (int rt = 0; rt < 4; ++rt) {
                    ah[rt] = *(const bf16x8*)&h1h[rt * 16 + lr][kk * 32 + g * 8];
                    al[rt] = *(const bf16x8*)&h1l[rt * 16 + lr][kk * 32 + g * 8];
                }
                #pragma unroll
                for (int rt = 0; rt < 4; ++rt)
                    #pragma unroll
                    for (int ct = 0; ct < 2; ++ct) {
                        f32x4 z = acc[rt][ct];
                        z = mfma16(ah[rt], w2bl[kk][ct], z);
                        z = mfma16(al[rt], w2bh[kk][ct], z);
                        acc[rt][ct] = mfma16(ah[rt], w2bh[kk][ct], z);
                    }
            }
            __syncthreads();
            #pragma unroll
            for (int ct = 0; ct < 2; ++ct) {
                const int col = cb + ct * 16 + lr;
                #pragma unroll
                for (int rt = 0; rt < 4; ++rt)
                    #pragma unroll
                    for (int i = 0; i < 4; ++i) {
                        float h = fmaxf(acc[rt][ct][i] + bb2[ct], 0.f);
                        ush hi = f2bf(h);
                        int row = rt * 16 + g * 4 + i;
                        h1h[row][col] = hi;
                        h1l[row][col] = f2bf(h - bf2f(hi));
                    }
            }
        }
        __syncthreads();

        // layer 3
        {
            const int hh = tid >> 7, r = tid & 127, n = r >> 1, o = r & 1;
            float s = 0.f;
            #pragma unroll
            for (int h8 = hh * 64; h8 < hh * 64 + 64; h8 += 8) {
                bf16x8 vh = *(const bf16x8*)&h1h[n][h8];
                bf16x8 vl = *(const bf16x8*)&h1l[n][h8];
                #pragma unroll
                for (int u = 0; u < 8; ++u) {
                    float hv = bf2f((ush)vh[u]) + bf2f((ush)vl[u]);
                    s += hv * w3s[(h8 + u) * 2 + o];
                }
            }
            p3[tid] = s;
        }
        __syncthreads();
        if (tid < 128) {
            const int n = tid >> 1, o = tid & 1;
            float v = (p3[tid] + p3[tid + 128]) * DT;
            float* dst = o ? th_ws : a_ws;
            dst[(size_t)(n0 + n) * NAUX + k] = v;
        }
    }
}

// ---------------------------------------------------------------------------
// K2: encoder via bf16 MFMA — LDS DIET: Xf removed (L1 A-frags read directly
// from global, coalesced 2KB/wave; epilogue xs re-read from global/L2).
// LDS 43 -> 33.8 KB => 4 blocks/CU, 16 waves/CU (was 3/12).
// ---------------------------------------------------------------------------
__global__ __launch_bounds__(256) void encm_kernel(
    const float* __restrict__ xs,
    const ush* __restrict__ W1T, const float* __restrict__ b1,
    const ush* __restrict__ W2T, const float* __restrict__ b2,
    const ush* __restrict__ W3T,
    float* __restrict__ y)
{
    __shared__ ush Hs[64 * 264];     // 33.8 KB (also reused as fp32 stage)

    const int tid = threadIdx.x;
    const int wv  = tid >> 6;
    const int ln  = tid & 63;
    const int lr  = ln & 15;
    const int g   = ln >> 4;
    const int cb  = wv * 64;
    const size_t row0 = (size_t)blockIdx.x * 64;

    // layer 1 (K=32): A-frags straight from global (wave reads contiguous 2KB)
    {
        f32x4 acc[4][4];
        bf16x8 bfr[4], afr[4];
        #pragma unroll
        for (int ct = 0; ct < 4; ++ct)
            bfr[ct] = *(const bf16x8*)&W1T[(cb + ct * 16 + lr) * 32 + g * 8];
        #pragma unroll
        for (int rt = 0; rt < 4; ++rt) {
            const float* xp = &xs[(row0 + rt * 16 + lr) * DIMX + g * 8];
            float4 u = *(const float4*)xp;
            float4 v = *(const float4*)(xp + 4);
            bf16x8 t;
            t[0]=(short)f2bf(u.x); t[1]=(short)f2bf(u.y); t[2]=(short)f2bf(u.z); t[3]=(short)f2bf(u.w);
            t[4]=(short)f2bf(v.x); t[5]=(short)f2bf(v.y); t[6]=(short)f2bf(v.z); t[7]=(short)f2bf(v.w);
            afr[rt] = t;
        }
        #pragma unroll
        for (int rt = 0; rt < 4; ++rt)
            #pragma unroll
            for (int ct = 0; ct < 4; ++ct) {
                f32x4 z = {0.f, 0.f, 0.f, 0.f};
                acc[rt][ct] = mfma16(afr[rt], bfr[ct], z);
            }
        #pragma unroll
        for (int ct = 0; ct < 4; ++ct) {
            const float bb = b1[cb + ct * 16 + lr];
            #pragma unroll
            for (int rt = 0; rt < 4; ++rt)
                #pragma unroll
                for (int i = 0; i < 4; ++i) {
                    float h = fmaxf(acc[rt][ct][i] + bb, 0.f);
                    Hs[(rt * 16 + g * 4 + i) * 264 + cb + ct * 16 + lr] = f2bf(h);
                }
        }
    }
    __syncthreads();

    int wrow[4], hoff[4];
    #pragma unroll
    for (int ct = 0; ct < 4; ++ct) wrow[ct] = (cb + ct * 16 + lr) * 256 + g * 8;
    #pragma unroll
    for (int rt = 0; rt < 4; ++rt) hoff[rt] = (rt * 16 + lr) * 264 + g * 8;

    // layer 2 (K=256)
    {
        f32x4 acc[4][4];
        #pragma unroll
        for (int rt = 0; rt < 4; ++rt)
            #pragma unroll
            for (int ct = 0; ct < 4; ++ct) acc[rt][ct] = (f32x4){0.f,0.f,0.f,0.f};
        #pragma unroll 2
        for (int kk = 0; kk < 8; ++kk) {
            bf16x8 bfr[4], afr[4];
            #pragma unroll
            for (int ct = 0; ct < 4; ++ct)
                bfr[ct] = *(const bf16x8*)&W2T[wrow[ct] + kk * 32];
            #pragma unroll
            for (int rt = 0; rt < 4; ++rt)
                afr[rt] = *(const bf16x8*)&Hs[hoff[rt] + kk * 32];
            #pragma unroll
            for (int rt = 0; rt < 4; ++rt)
                #pragma unroll
                for (int ct = 0; ct < 4; ++ct)
                    acc[rt][ct] = mfma16(afr[rt], bfr[ct], acc[rt][ct]);
        }
        __syncthreads();
        #pragma unroll
        for (int ct = 0; ct < 4; ++ct) {
            const float bb = b2[cb + ct * 16 + lr];
            #pragma unroll
            for (int rt = 0; rt < 4; ++rt)
                #pragma unroll
                for (int i = 0; i < 4; ++i) {
                    float h = fmaxf(acc[rt][ct][i] + bb, 0.f);
                    Hs[(rt * 16 + g * 4 + i) * 264 + cb + ct * 16 + lr] = f2bf(h);
                }
        }
    }
    __syncthreads();

    // layer 3 (K=256) + coalesced two-pass store (skip t=0 e-cols)
    {
        f32x4 acc[4][4];
        #pragma unroll
        for (int rt = 0; rt < 4; ++rt)
            #pragma unroll
            for (int ct = 0; ct < 4; ++ct) acc[rt][ct] = (f32x4){0.f,0.f,0.f,0.f};
        #pragma unroll 2
        for (int kk = 0; kk < 8; ++kk) {
            bf16x8 bfr[4], afr[4];
            #pragma unroll
            for (int ct = 0; ct < 4; ++ct)
                bfr[ct] = *(const bf16x8*)&W3T[wrow[ct] + kk * 32];
            #pragma unroll
            for (int rt = 0; rt < 4; ++rt)
                afr[rt] = *(const bf16x8*)&Hs[hoff[rt] + kk * 32];
            #pragma unroll
            for (int rt = 0; rt < 4; ++rt)
                #pragma unroll
                for (int ct = 0; ct < 4; ++ct)
                    acc[rt][ct] = mfma16(afr[rt], bfr[ct], acc[rt][ct]);
        }
        __syncthreads();

        float* HsF = (float*)Hs;
        const int r  = tid >> 3;
        const int ce = tid & 7;

        #pragma unroll
        for (int p = 0; p < 2; ++p) {
            #pragma unroll
            for (int rt = 2 * p; rt < 2 * p + 2; ++rt)
                #pragma unroll
                for (int ct = 0; ct < 4; ++ct)
                    #pragma unroll
                    for (int i = 0; i < 4; ++i)
                        HsF[((rt - 2 * p) * 16 + g * 4 + i) * 264 + cb + ct * 16 + lr]
                            = acc[rt][ct][i];
            __syncthreads();
            const int rloc = p * 32 + r;
            float* dstrow = &y[(row0 + rloc) * OUTC];
            #pragma unroll
            for (int j = 0; j < 9; ++j) {
                int f4 = j * 8 + ce;
                float4 v;
                if (f4 < 8) v = *(const float4*)&xs[(row0 + rloc) * DIMX + f4 * 4];
                else        v = *(const float4*)&HsF[r * 264 + (f4 - 8) * 4];
                if (!(rloc == 0 && f4 >= 8))
                    *(float4*)&dstrow[f4 * 4] = v;
            }
            __syncthreads();
        }
    }
}

// ---------------------------------------------------------------------------
// K3: scan3 (R11-proven) — closed-form z^t scan + fused fp32 readout.
// ---------------------------------------------------------------------------
__global__ __launch_bounds__(256) void scan3_kernel(
    const float* __restrict__ xs,
    const float* __restrict__ a_ws, const float* __restrict__ th_ws,
    const float* __restrict__ cwt,
    const float* __restrict__ y,
    float* __restrict__ yp)
{
    __shared__ float ys_lds[16][256];

    const int n = blockIdx.x >> 2;
    const int q = blockIdx.x & 3;
    const int e = threadIdx.x;
    const int k = e >> 1;

    const float* yrow0 = y + (size_t)n * T_SEQ * OUTC + DIMX;
    float2 y0 = *(const float2*)&yrow0[e & ~1];
    const float a  = a_ws [n * NAUX + k];
    const float th = th_ws[n * NAUX + k];

    const float m = expf(a);
    float ss, cc; sincosf(th, &ss, &cc);
    const float zr = m * cc, zi = m * ss;

    float pr = zr, pi = zi;
    #pragma unroll
    for (int s2 = 0; s2 < 4; ++s2) {
        float nr = pr * pr - pi * pi;
        pi = 2.f * pr * pi; pr = nr;
    }
    float wr = 1.f, wi = 0.f;
    for (int j = 0; j < q; ++j) {
        float nr = wr * pr - wi * pi;
        wi = wr * pi + wi * pr; wr = nr;
    }

    const bool imag = e & 1;
    float* ypn = yp + (size_t)n * T_SEQ * OUTC;

    #pragma unroll 4
    for (int tl = 0; tl < 16; ++tl) {
        const int t = q * 16 + tl;
        float val = imag ? (y0.x * wi + y0.y * wr)
                         : (y0.x * wr - y0.y * wi);
        ypn[(size_t)t * OUTC + DIMX + e] = val;
        ys_lds[tl][(e + ((tl >> 1) & 7) * 4) & 255] = val;
        float nwr = wr * zr - wi * zi;
        wi = wr * zi + wi * zr;
        wr = nwr;
    }
    __syncthreads();

    const int d   = e >> 3;
    const int tg  = e & 7;
    const int tl0 = tg * 2, tl1 = tl0 + 1;
    const float* cwd = cwt + d * 256;
    const int rot = tg * 4;

    float s0 = 0.f, s1 = 0.f;
    #pragma unroll 8
    for (int l = 0; l < 256; l += 4) {
        const int c0 = (l + rot) & 255;
        float4 wv = *(const float4*)&cwd[l];
        float4 ya = *(const float4*)&ys_lds[tl0][c0];
        float4 yb = *(const float4*)&ys_lds[tl1][c0];
        s0 += ya.x * wv.x + ya.y * wv.y + ya.z * wv.z + ya.w * wv.w;
        s1 += yb.x * wv.x + yb.y * wv.y + yb.z * wv.z + yb.w * wv.w;
    }
    const int t0 = q * 16 + tl0;
    const int t1 = q * 16 + tl1;
    float o0 = (t0 == 0) ? xs[(size_t)n * T_SEQ * DIMX + d] : s0;
    ypn[(size_t)t0 * OUTC + d] = o0;
    ypn[(size_t)t1 * OUTC + d] = s1;
}

// ---------------------------------------------------------------------------
extern "C" void kernel_launch(void* const* d_in, const int* in_sizes, int n_in,
                              void* d_out, int out_size, void* d_ws, size_t ws_size,
                              hipStream_t stream)
{
    const float* xs   = (const float*)d_in[0];
    const float* eW1  = (const float*)d_in[1];
    const float* eb1  = (const float*)d_in[2];
    const float* eW2  = (const float*)d_in[3];
    const float* eb2  = (const float*)d_in[4];
    const float* eW3  = (const float*)d_in[5];
    const float* aW1  = (const float*)d_in[6];
    const float* ab1  = (const float*)d_in[7];
    const float* aW2  = (const float*)d_in[8];
    const float* ab2  = (const float*)d_in[9];
    const float* aW3  = (const float*)d_in[10];
    const float* C_W  = (const float*)d_in[11];

    float* y  = (float*)d_out;
    float* yp = y + (size_t)N_SEQ * T_SEQ * OUTC;

    float* a_ws  = (float*)d_ws;
    float* th_ws = a_ws + (size_t)N_SEQ * NAUX;
    ush* encw = (ush*)(th_ws + (size_t)N_SEQ * NAUX);
    ush* W1T = encw;
    ush* W2T = encw + 8192;
    ush* W3T = encw + 8192 + 65536;
    ush* a1h = encw + CV_ENC;
    ush* a1l = a1h + 524288;
    ush* a2h = a1l + 524288;
    ush* a2l = a2h + 2097152;
    float* cwt = (float*)(a2l + 2097152);

    prep_kernel<<<PREP_CONV_BLOCKS + PREP_TR_BLOCKS + PREP_ENC0_BLOCKS, 256, 0, stream>>>(
        eW1, eb1, eW2, eb2, eW3, C_W, aW1, aW2, xs,
        encw, cwt, a1h, a1l, a2h, a2l, y);
    auxm_kernel<<<512, 256, 0, stream>>>(
        xs, a1h, a1l, ab1, a2h, a2l, ab2, aW3, a_ws, th_ws);
    encm_kernel<<<N_SEQ * T_SEQ / 64, 256, 0, stream>>>(
        xs, W1T, eb1, W2T, eb2, W3T, y);
    scan3_kernel<<<N_SEQ * 4, 256, 0, stream>>>(xs, a_ws, th_ws, cwt, y, yp);
}

// Round 14
// 156.005 us; speedup vs baseline: 1.0752x; 1.0480x over previous
//
#include <hip/hip_runtime.h>
#include <math.h>

#define N_SEQ 1024
#define T_SEQ 64
#define DIMX  32
#define LDIM  256
#define NAUX  128
#define AUXH  128
#define ENCH  256
#define OUTC  288           // DIMX + LDIM
#define DT    0.01f

typedef short bf16x8 __attribute__((ext_vector_type(8)));
typedef float f32x4  __attribute__((ext_vector_type(4)));
typedef unsigned short ush;

__device__ __forceinline__ ush f2bf(float f) {
    unsigned u = __builtin_bit_cast(unsigned, f);
    unsigned r = u + 0x7fffu + ((u >> 16) & 1u);   // RNE
    return (ush)(r >> 16);
}
__device__ __forceinline__ float bf2f(ush h) {
    unsigned u = ((unsigned)h) << 16;
    return __builtin_bit_cast(float, u);
}
__device__ __forceinline__ f32x4 mfma16(bf16x8 a, bf16x8 b, f32x4 c) {
    return __builtin_amdgcn_mfma_f32_16x16x32_bf16(a, b, c, 0, 0, 0);
}

// ---------------------------------------------------------------------------
// K0 "prep": 3 independent jobs, branch on blockIdx (validated R11/R13) —
//   [0,576)      encoder weights -> bf16 T; C_W -> fp32 T
//   [576,3136)   aux W1/W2 -> hi/lo bf16 T (32x32 LDS tile transpose)
//   [3136,3392)  enc0: fp32 encoder for the 1024 t=0 rows (4 rows/block)
// ---------------------------------------------------------------------------
#define CV_ENC   139264
#define PREP_CONV_BLOCKS 576
#define PREP_TR_BLOCKS   2560
#define PREP_ENC0_BLOCKS 256
__global__ __launch_bounds__(256) void prep_kernel(
    const float* __restrict__ eW1, const float* __restrict__ eb1,
    const float* __restrict__ eW2, const float* __restrict__ eb2,
    const float* __restrict__ eW3, const float* __restrict__ C_W,
    const float* __restrict__ aW1, const float* __restrict__ aW2,
    const float* __restrict__ xs,
    ush* __restrict__ encw, float* __restrict__ cwt,
    ush* __restrict__ a1h, ush* __restrict__ a1l,
    ush* __restrict__ a2h, ush* __restrict__ a2l,
    float* __restrict__ y)
{
    __shared__ float psm[1152];
    const int b   = blockIdx.x;
    const int tid = threadIdx.x;

    if (b < PREP_CONV_BLOCKS) {
        const int idx = b * 256 + tid;
        if (idx < 8192) {
            int c = idx >> 5, k = idx & 31;
            encw[idx] = f2bf(eW1[k * ENCH + c]);
        } else if (idx < 8192 + 65536) {
            int t = idx - 8192; int c = t >> 8, k = t & 255;
            encw[idx] = f2bf(eW2[k * ENCH + c]);
        } else if (idx < CV_ENC) {
            int t = idx - (8192 + 65536); int c = t >> 8, k = t & 255;
            encw[idx] = f2bf(eW3[k * LDIM + c]);
        } else if (idx < CV_ENC + 8192) {
            int t = idx - CV_ENC; int d = t >> 8, l = t & 255;
            cwt[t] = C_W[l * DIMX + d];
        }
        return;
    }

    if (b < PREP_CONV_BLOCKS + PREP_TR_BLOCKS) {
        float (*tile)[33] = (float(*)[33])psm;
        const int bb0 = b - PREP_CONV_BLOCKS;
        const float* src; ush *dh, *dl; int R, j0, r0;
        if (bb0 < 512) {
            int k = bb0 >> 2; j0 = (bb0 & 3) * 32; r0 = 0; R = 32;
            src = aW1 + (size_t)k * 4096;
            dh = a1h + (size_t)k * 4096; dl = a1l + (size_t)k * 4096;
        } else {
            int bb = bb0 - 512;
            int k = bb >> 4; j0 = ((bb >> 2) & 3) * 32; r0 = (bb & 3) * 32; R = 128;
            src = aW2 + (size_t)k * 16384;
            dh = a2h + (size_t)k * 16384; dl = a2l + (size_t)k * 16384;
        }
        for (int i = tid; i < 1024; i += 256) {
            int rr = i >> 5, jj = i & 31;
            tile[rr][jj] = src[(r0 + rr) * 128 + j0 + jj];
        }
        __syncthreads();
        for (int i = tid; i < 1024; i += 256) {
            int jj = i >> 5, rr = i & 31;
            float w = tile[rr][jj];
            ush hi = f2bf(w);
            int off = (j0 + jj) * R + r0 + rr;
            dh[off] = hi;
            dl[off] = f2bf(w - bf2f(hi));
        }
        return;
    }

    // ---- enc0 ----
    {
        float* Xs  = psm;
        float* Hsf = psm + 128;
        const int c  = tid;
        const int n0 = (b - PREP_CONV_BLOCKS - PREP_TR_BLOCKS) * 4;

        if (tid < 32) {
            int r = tid >> 3, q = tid & 7;
            *(float4*)&Xs[r * 32 + q * 4] =
                *(const float4*)&xs[(size_t)(n0 + r) * (T_SEQ * DIMX) + q * 4];
        }
        __syncthreads();

        float acc[4];
        {
            float w[32];
            #pragma unroll
            for (int d = 0; d < 32; ++d) w[d] = eW1[d * ENCH + c];
            const float bb = eb1[c];
            #pragma unroll
            for (int r = 0; r < 4; ++r) {
                float a = bb;
                #pragma unroll
                for (int d4 = 0; d4 < 8; ++d4) {
                    float4 xv = *(const float4*)&Xs[r * 32 + d4 * 4];
                    a += xv.x * w[d4*4] + xv.y * w[d4*4+1] + xv.z * w[d4*4+2] + xv.w * w[d4*4+3];
                }
                acc[r] = a;
            }
            #pragma unroll
            for (int r = 0; r < 4; ++r) Hsf[r * 256 + c] = fmaxf(acc[r], 0.f);
        }
        __syncthreads();
        {
            const float bb = eb2[c];
            #pragma unroll
            for (int r = 0; r < 4; ++r) acc[r] = bb;
            for (int hc = 0; hc < 8; ++hc) {
                float w[32];
                #pragma unroll
                for (int i = 0; i < 32; ++i) w[i] = eW2[(hc * 32 + i) * ENCH + c];
                #pragma unroll
                for (int r = 0; r < 4; ++r) {
                    float a = acc[r];
                    #pragma unroll
                    for (int h4 = 0; h4 < 8; ++h4) {
                        float4 hv = *(const float4*)&Hsf[r * 256 + hc * 32 + h4 * 4];
                        a += hv.x * w[h4*4] + hv.y * w[h4*4+1] + hv.z * w[h4*4+2] + hv.w * w[h4*4+3];
                    }
                    acc[r] = a;
                }
            }
            __syncthreads();
            #pragma unroll
            for (int r = 0; r < 4; ++r) Hsf[r * 256 + c] = fmaxf(acc[r], 0.f);
        }
        __syncthreads();
        {
            #pragma unroll
            for (int r = 0; r < 4; ++r) acc[r] = 0.f;
            for (int hc = 0; hc < 8; ++hc) {
                float w[32];
                #pragma unroll
                for (int i = 0; i < 32; ++i) w[i] = eW3[(hc * 32 + i) * LDIM + c];
                #pragma unroll
                for (int r = 0; r < 4; ++r) {
                    float a = acc[r];
                    #pragma unroll
                    for (int h4 = 0; h4 < 8; ++h4) {
                        float4 hv = *(const float4*)&Hsf[r * 256 + hc * 32 + h4 * 4];
                        a += hv.x * w[h4*4] + hv.y * w[h4*4+1] + hv.z * w[h4*4+2] + hv.w * w[h4*4+3];
                    }
                    acc[r] = a;
                }
            }
        }
        #pragma unroll
        for (int r = 0; r < 4; ++r)
            y[((size_t)(n0 + r) * T_SEQ) * OUTC + DIMX + c] = acc[r];
    }
}

// ---------------------------------------------------------------------------
// K1 "fused": auxm [0,512) + encm [512,1536) — one dispatch, both branches
// verbatim from their validated standalone forms (R11 auxm, R13 encm).
// LDS aliased: 47104 B (auxm's footprint; encm uses first 33792 B).
// ---------------------------------------------------------------------------
__global__ __launch_bounds__(256) void fused_kernel(
    const float* __restrict__ xs,
    const ush* __restrict__ W1h, const ush* __restrict__ W1l,
    const float* __restrict__ ab1,
    const ush* __restrict__ W2h, const ush* __restrict__ W2l,
    const float* __restrict__ ab2,
    const float* __restrict__ aW3,
    float* __restrict__ a_ws, float* __restrict__ th_ws,
    const ush* __restrict__ W1T, const float* __restrict__ eb1,
    const ush* __restrict__ W2T, const float* __restrict__ eb2,
    const ush* __restrict__ W3T,
    float* __restrict__ y)
{
    __shared__ __align__(16) char smem[47104];
    const int tid = threadIdx.x;
    const int wv  = tid >> 6;
    const int ln  = tid & 63;
    const int lr  = ln & 15;
    const int g   = ln >> 4;

    if (blockIdx.x < 512) {
        // =================== auxm (R11-validated) ===================
        ush (*x0h)[40]  = (ush(*)[40]) (smem);
        ush (*x0l)[40]  = (ush(*)[40]) (smem + 5120);
        ush (*h1h)[136] = (ush(*)[136])(smem + 10240);
        ush (*h1l)[136] = (ush(*)[136])(smem + 27648);
        float* w3s      = (float*)     (smem + 45056);
        float* p3       = (float*)     (smem + 46080);

        const int k  = blockIdx.x >> 2;
        const int qn = blockIdx.x & 3;
        const int cb = wv * 32;

        bf16x8 w1bh[2], w1bl[2], w2bh[4][2], w2bl[4][2];
        {
            const ush* W1hk = W1h + (size_t)k * 4096;
            const ush* W1lk = W1l + (size_t)k * 4096;
            #pragma unroll
            for (int ct = 0; ct < 2; ++ct) {
                int off = (cb + ct * 16 + lr) * 32 + g * 8;
                w1bh[ct] = *(const bf16x8*)&W1hk[off];
                w1bl[ct] = *(const bf16x8*)&W1lk[off];
            }
            const ush* W2hk = W2h + (size_t)k * 16384;
            const ush* W2lk = W2l + (size_t)k * 16384;
            #pragma unroll
            for (int kk = 0; kk < 4; ++kk)
                #pragma unroll
                for (int ct = 0; ct < 2; ++ct) {
                    int off = (cb + ct * 16 + lr) * 128 + kk * 32 + g * 8;
                    w2bh[kk][ct] = *(const bf16x8*)&W2hk[off];
                    w2bl[kk][ct] = *(const bf16x8*)&W2lk[off];
                }
        }
        w3s[tid] = aW3[(size_t)k * (AUXH * 2) + tid];

        const float bb1[2] = { ab1[k * 128 + cb + lr], ab1[k * 128 + cb + 16 + lr] };
        const float bb2[2] = { ab2[k * 128 + cb + lr], ab2[k * 128 + cb + 16 + lr] };

        for (int t8 = 0; t8 < 4; ++t8) {
            const int n0 = qn * 256 + t8 * 64;
            __syncthreads();

            for (int i = tid; i < 512; i += 256) {
                int r = i >> 3, qd = i & 7;
                float4 v = *(const float4*)&xs[(size_t)(n0 + r) * (T_SEQ * DIMX) + qd * 4];
                short4 hs, ls;
                float vv[4] = {v.x, v.y, v.z, v.w};
                short* hp = (short*)&hs; short* lp = (short*)&ls;
                #pragma unroll
                for (int u = 0; u < 4; ++u) {
                    ush hi = f2bf(vv[u]);
                    hp[u] = (short)hi;
                    lp[u] = (short)f2bf(vv[u] - bf2f(hi));
                }
                *(short4*)&x0h[r][qd * 4] = hs;
                *(short4*)&x0l[r][qd * 4] = ls;
            }
            __syncthreads();

            // layer 1
            {
                f32x4 acc[4][2];
                #pragma unroll
                for (int rt = 0; rt < 4; ++rt) {
                    bf16x8 ah = *(const bf16x8*)&x0h[rt * 16 + lr][g * 8];
                    bf16x8 al = *(const bf16x8*)&x0l[rt * 16 + lr][g * 8];
                    #pragma unroll
                    for (int ct = 0; ct < 2; ++ct) {
                        f32x4 z = {0.f, 0.f, 0.f, 0.f};
                        z = mfma16(ah, w1bl[ct], z);
                        z = mfma16(al, w1bh[ct], z);
                        acc[rt][ct] = mfma16(ah, w1bh[ct], z);
                    }
                }
                #pragma unroll
                for (int ct = 0; ct < 2; ++ct) {
                    const int col = cb + ct * 16 + lr;
                    #pragma unroll
                    for (int rt = 0; rt < 4; ++rt)
                        #pragma unroll
                        for (int i = 0; i < 4; ++i) {
                            float h = fmaxf(acc[rt][ct][i] + bb1[ct], 0.f);
                            ush hi = f2bf(h);
                            int row = rt * 16 + g * 4 + i;
                            h1h[row][col] = hi;
                            h1l[row][col] = f2bf(h - bf2f(hi));
                        }
                }
            }
            __syncthreads();

            // layer 2
            {
                f32x4 acc[4][2];
                #pragma unroll
                for (int rt = 0; rt < 4; ++rt)
                    #pragma unroll
                    for (int ct = 0; ct < 2; ++ct) acc[rt][ct] = (f32x4){0.f,0.f,0.f,0.f};

                #pragma unroll
                for (int kk = 0; kk < 4; ++kk) {
                    bf16x8 ah[4], al[4];
                    #pragma unroll
                    for (int rt = 0; rt < 4; ++rt) {
                        ah[rt] = *(const bf16x8*)&h1h[rt * 16 + lr][kk * 32 + g * 8];
                        al[rt] = *(const bf16x8*)&h1l[rt * 16 + lr][kk * 32 + g * 8];
                    }
                    #pragma unroll
                    for (int rt = 0; rt < 4; ++rt)
                        #pragma unroll
                        for (int ct = 0; ct < 2; ++ct) {
                            f32x4 z = acc[rt][ct];
                            z = mfma16(ah[rt], w2bl[kk][ct], z);
                            z = mfma16(al[rt], w2bh[kk][ct], z);
                            acc[rt][ct] = mfma16(ah[rt], w2bh[kk][ct], z);
                        }
                }
                __syncthreads();
                #pragma unroll
                for (int ct = 0; ct < 2; ++ct) {
                    const int col = cb + ct * 16 + lr;
                    #pragma unroll
                    for (int rt = 0; rt < 4; ++rt)
                        #pragma unroll
                        for (int i = 0; i < 4; ++i) {
                            float h = fmaxf(acc[rt][ct][i] + bb2[ct], 0.f);
                            ush hi = f2bf(h);
                            int row = rt * 16 + g * 4 + i;
                            h1h[row][col] = hi;
                            h1l[row][col] = f2bf(h - bf2f(hi));
                        }
                }
            }
            __syncthreads();

            // layer 3
            {
                const int hh = tid >> 7, r = tid & 127, n = r >> 1, o = r & 1;
                float s = 0.f;
                #pragma unroll
                for (int h8 = hh * 64; h8 < hh * 64 + 64; h8 += 8) {
                    bf16x8 vh = *(const bf16x8*)&h1h[n][h8];
                    bf16x8 vl = *(const bf16x8*)&h1l[n][h8];
                    #pragma unroll
                    for (int u = 0; u < 8; ++u) {
                        float hv = bf2f((ush)vh[u]) + bf2f((ush)vl[u]);
                        s += hv * w3s[(h8 + u) * 2 + o];
                    }
                }
                p3[tid] = s;
            }
            __syncthreads();
            if (tid < 128) {
                const int n = tid >> 1, o = tid & 1;
                float v = (p3[tid] + p3[tid + 128]) * DT;
                float* dst = o ? th_ws : a_ws;
                dst[(size_t)(n0 + n) * NAUX + k] = v;
            }
        }
        return;
    }

    // =================== encm (R13-validated) ===================
    {
        ush* Hs = (ush*)smem;          // 64*264 ush = 33792 B

        const int cb  = wv * 64;
        const size_t row0 = (size_t)(blockIdx.x - 512) * 64;

        // layer 1 (K=32): A-frags from global
        {
            f32x4 acc[4][4];
            bf16x8 bfr[4], afr[4];
            #pragma unroll
            for (int ct = 0; ct < 4; ++ct)
                bfr[ct] = *(const bf16x8*)&W1T[(cb + ct * 16 + lr) * 32 + g * 8];
            #pragma unroll
            for (int rt = 0; rt < 4; ++rt) {
                const float* xp = &xs[(row0 + rt * 16 + lr) * DIMX + g * 8];
                float4 u = *(const float4*)xp;
                float4 v = *(const float4*)(xp + 4);
                bf16x8 t;
                t[0]=(short)f2bf(u.x); t[1]=(short)f2bf(u.y); t[2]=(short)f2bf(u.z); t[3]=(short)f2bf(u.w);
                t[4]=(short)f2bf(v.x); t[5]=(short)f2bf(v.y); t[6]=(short)f2bf(v.z); t[7]=(short)f2bf(v.w);
                afr[rt] = t;
            }
            #pragma unroll
            for (int rt = 0; rt < 4; ++rt)
                #pragma unroll
                for (int ct = 0; ct < 4; ++ct) {
                    f32x4 z = {0.f, 0.f, 0.f, 0.f};
                    acc[rt][ct] = mfma16(afr[rt], bfr[ct], z);
                }
            #pragma unroll
            for (int ct = 0; ct < 4; ++ct) {
                const float bb = eb1[cb + ct * 16 + lr];
                #pragma unroll
                for (int rt = 0; rt < 4; ++rt)
                    #pragma unroll
                    for (int i = 0; i < 4; ++i) {
                        float h = fmaxf(acc[rt][ct][i] + bb, 0.f);
                        Hs[(rt * 16 + g * 4 + i) * 264 + cb + ct * 16 + lr] = f2bf(h);
                    }
            }
        }
        __syncthreads();

        int wrow[4], hoff[4];
        #pragma unroll
        for (int ct = 0; ct < 4; ++ct) wrow[ct] = (cb + ct * 16 + lr) * 256 + g * 8;
        #pragma unroll
        for (int rt = 0; rt < 4; ++rt) hoff[rt] = (rt * 16 + lr) * 264 + g * 8;

        // layer 2 (K=256)
        {
            f32x4 acc[4][4];
            #pragma unroll
            for (int rt = 0; rt < 4; ++rt)
                #pragma unroll
                for (int ct = 0; ct < 4; ++ct) acc[rt][ct] = (f32x4){0.f,0.f,0.f,0.f};
            #pragma unroll 2
            for (int kk = 0; kk < 8; ++kk) {
                bf16x8 bfr[4], afr[4];
                #pragma unroll
                for (int ct = 0; ct < 4; ++ct)
                    bfr[ct] = *(const bf16x8*)&W2T[wrow[ct] + kk * 32];
                #pragma unroll
                for (int rt = 0; rt < 4; ++rt)
                    afr[rt] = *(const bf16x8*)&Hs[hoff[rt] + kk * 32];
                #pragma unroll
                for (int rt = 0; rt < 4; ++rt)
                    #pragma unroll
                    for (int ct = 0; ct < 4; ++ct)
                        acc[rt][ct] = mfma16(afr[rt], bfr[ct], acc[rt][ct]);
            }
            __syncthreads();
            #pragma unroll
            for (int ct = 0; ct < 4; ++ct) {
                const float bb = eb2[cb + ct * 16 + lr];
                #pragma unroll
                for (int rt = 0; rt < 4; ++rt)
                    #pragma unroll
                    for (int i = 0; i < 4; ++i) {
                        float h = fmaxf(acc[rt][ct][i] + bb, 0.f);
                        Hs[(rt * 16 + g * 4 + i) * 264 + cb + ct * 16 + lr] = f2bf(h);
                    }
            }
        }
        __syncthreads();

        // layer 3 (K=256) + coalesced two-pass store (skip t=0 e-cols)
        {
            f32x4 acc[4][4];
            #pragma unroll
            for (int rt = 0; rt < 4; ++rt)
                #pragma unroll
                for (int ct = 0; ct < 4; ++ct) acc[rt][ct] = (f32x4){0.f,0.f,0.f,0.f};
            #pragma unroll 2
            for (int kk = 0; kk < 8; ++kk) {
                bf16x8 bfr[4], afr[4];
                #pragma unroll
                for (int ct = 0; ct < 4; ++ct)
                    bfr[ct] = *(const bf16x8*)&W3T[wrow[ct] + kk * 32];
                #pragma unroll
                for (int rt = 0; rt < 4; ++rt)
                    afr[rt] = *(const bf16x8*)&Hs[hoff[rt] + kk * 32];
                #pragma unroll
                for (int rt = 0; rt < 4; ++rt)
                    #pragma unroll
                    for (int ct = 0; ct < 4; ++ct)
                        acc[rt][ct] = mfma16(afr[rt], bfr[ct], acc[rt][ct]);
            }
            __syncthreads();

            float* HsF = (float*)Hs;
            const int r  = tid >> 3;
            const int ce = tid & 7;

            #pragma unroll
            for (int p = 0; p < 2; ++p) {
                #pragma unroll
                for (int rt = 2 * p; rt < 2 * p + 2; ++rt)
                    #pragma unroll
                    for (int ct = 0; ct < 4; ++ct)
                        #pragma unroll
                        for (int i = 0; i < 4; ++i)
                            HsF[((rt - 2 * p) * 16 + g * 4 + i) * 264 + cb + ct * 16 + lr]
                                = acc[rt][ct][i];
                __syncthreads();
                const int rloc = p * 32 + r;
                float* dstrow = &y[(row0 + rloc) * OUTC];
                #pragma unroll
                for (int j = 0; j < 9; ++j) {
                    int f4 = j * 8 + ce;
                    float4 v;
                    if (f4 < 8) v = *(const float4*)&xs[(row0 + rloc) * DIMX + f4 * 4];
                    else        v = *(const float4*)&HsF[r * 264 + (f4 - 8) * 4];
                    if (!(rloc == 0 && f4 >= 8))
                        *(float4*)&dstrow[f4 * 4] = v;
                }
                __syncthreads();
            }
        }
    }
}

// ---------------------------------------------------------------------------
// K2: scan3 (proven) — closed-form z^t scan + fused fp32 readout.
// ---------------------------------------------------------------------------
__global__ __launch_bounds__(256) void scan3_kernel(
    const float* __restrict__ xs,
    const float* __restrict__ a_ws, const float* __restrict__ th_ws,
    const float* __restrict__ cwt,
    const float* __restrict__ y,
    float* __restrict__ yp)
{
    __shared__ float ys_lds[16][256];

    const int n = blockIdx.x >> 2;
    const int q = blockIdx.x & 3;
    const int e = threadIdx.x;
    const int k = e >> 1;

    const float* yrow0 = y + (size_t)n * T_SEQ * OUTC + DIMX;
    float2 y0 = *(const float2*)&yrow0[e & ~1];
    const float a  = a_ws [n * NAUX + k];
    const float th = th_ws[n * NAUX + k];

    const float m = expf(a);
    float ss, cc; sincosf(th, &ss, &cc);
    const float zr = m * cc, zi = m * ss;

    float pr = zr, pi = zi;
    #pragma unroll
    for (int s2 = 0; s2 < 4; ++s2) {
        float nr = pr * pr - pi * pi;
        pi = 2.f * pr * pi; pr = nr;
    }
    float wr = 1.f, wi = 0.f;
    for (int j = 0; j < q; ++j) {
        float nr = wr * pr - wi * pi;
        wi = wr * pi + wi * pr; wr = nr;
    }

    const bool imag = e & 1;
    float* ypn = yp + (size_t)n * T_SEQ * OUTC;

    #pragma unroll 4
    for (int tl = 0; tl < 16; ++tl) {
        const int t = q * 16 + tl;
        float val = imag ? (y0.x * wi + y0.y * wr)
                         : (y0.x * wr - y0.y * wi);
        ypn[(size_t)t * OUTC + DIMX + e] = val;
        ys_lds[tl][(e + ((tl >> 1) & 7) * 4) & 255] = val;
        float nwr = wr * zr - wi * zi;
        wi = wr * zi + wi * zr;
        wr = nwr;
    }
    __syncthreads();

    const int d   = e >> 3;
    const int tg  = e & 7;
    const int tl0 = tg * 2, tl1 = tl0 + 1;
    const float* cwd = cwt + d * 256;
    const int rot = tg * 4;

    float s0 = 0.f, s1 = 0.f;
    #pragma unroll 8
    for (int l = 0; l < 256; l += 4) {
        const int c0 = (l + rot) & 255;
        float4 wv = *(const float4*)&cwd[l];
        float4 ya = *(const float4*)&ys_lds[tl0][c0];
        float4 yb = *(const float4*)&ys_lds[tl1][c0];
        s0 += ya.x * wv.x + ya.y * wv.y + ya.z * wv.z + ya.w * wv.w;
        s1 += yb.x * wv.x + yb.y * wv.y + yb.z * wv.z + yb.w * wv.w;
    }
    const int t0 = q * 16 + tl0;
    const int t1 = q * 16 + tl1;
    float o0 = (t0 == 0) ? xs[(size_t)n * T_SEQ * DIMX + d] : s0;
    ypn[(size_t)t0 * OUTC + d] = o0;
    ypn[(size_t)t1 * OUTC + d] = s1;
}

// ---------------------------------------------------------------------------
extern "C" void kernel_launch(void* const* d_in, const int* in_sizes, int n_in,
                              void* d_out, int out_size, void* d_ws, size_t ws_size,
                              hipStream_t stream)
{
    const float* xs   = (const float*)d_in[0];
    const float* eW1  = (const float*)d_in[1];
    const float* eb1  = (const float*)d_in[2];
    const float* eW2  = (const float*)d_in[3];
    const float* eb2  = (const float*)d_in[4];
    const float* eW3  = (const float*)d_in[5];
    const float* aW1  = (const float*)d_in[6];
    const float* ab1  = (const float*)d_in[7];
    const float* aW2  = (const float*)d_in[8];
    const float* ab2  = (const float*)d_in[9];
    const float* aW3  = (const float*)d_in[10];
    const float* C_W  = (const float*)d_in[11];

    float* y  = (float*)d_out;
    float* yp = y + (size_t)N_SEQ * T_SEQ * OUTC;

    float* a_ws  = (float*)d_ws;
    float* th_ws = a_ws + (size_t)N_SEQ * NAUX;
    ush* encw = (ush*)(th_ws + (size_t)N_SEQ * NAUX);
    ush* W1T = encw;
    ush* W2T = encw + 8192;
    ush* W3T = encw + 8192 + 65536;
    ush* a1h = encw + CV_ENC;
    ush* a1l = a1h + 524288;
    ush* a2h = a1l + 524288;
    ush* a2l = a2h + 2097152;
    float* cwt = (float*)(a2l + 2097152);

    prep_kernel<<<PREP_CONV_BLOCKS + PREP_TR_BLOCKS + PREP_ENC0_BLOCKS, 256, 0, stream>>>(
        eW1, eb1, eW2, eb2, eW3, C_W, aW1, aW2, xs,
        encw, cwt, a1h, a1l, a2h, a2l, y);
    fused_kernel<<<1536, 256, 0, stream>>>(
        xs, a1h, a1l, ab1, a2h, a2l, ab2, aW3, a_ws, th_ws,
        W1T, eb1, W2T, eb2, W3T, y);
    scan3_kernel<<<N_SEQ * 4, 256, 0, stream>>>(xs, a_ws, th_ws, cwt, y, yp);
}